// Round 1
// baseline (201.393 us; speedup 1.0000x reference)
//
#include <hip/hip_runtime.h>
#include <stdint.h>

#define B_    16
#define AT_   96
#define NBR_  12
#define FN_   64
#define FE_   64
#define M1    (B_*AT_*NBR_)   /* 18432 */
#define R_    (B_*AT_)        /* 1536  */
#define K1Q   128             /* layer-1 input features (bytes per row) */
#define N1    512             /* H1 */
#define K2Q   512
#define N2    128
#define SPLIT2 4

typedef _Float16 f16x8 __attribute__((ext_vector_type(8)));
typedef float    f32x4 __attribute__((ext_vector_type(4)));
typedef __attribute__((address_space(1))) const void gconst_void;
typedef __attribute__((address_space(3))) void lds_void;

/* ---- workspace layout (bytes) ---- */
#define OFF_SCAL  0u
#define OFF_B1R   256u                                  /* fp32 512  */
#define OFF_B2R   (OFF_B1R + 2048u)                     /* fp32 128  */
#define OFF_Q1    4096u                                 /* u8 M1*128 = 2.25 MB */
#define OFF_W1E   (OFF_Q1  + (size_t)M1*K1Q)            /* fp16 512*1024 = 1 MB */
#define OFF_W2E   (OFF_W1E + (size_t)N1*K1Q*8*2)        /* fp16 128*4096 = 1 MB */
#define OFF_Q2    (OFF_W2E + (size_t)N2*K2Q*8*2)        /* u8 M1*512 = 9 MB */
#define OFF_H     (OFF_Q2  + (size_t)M1*K2Q)            /* fp32 M1*512 = 37.75 MB */
#define OFF_ZP    OFF_H                                  /* fp16 4*M1*128 = 18.9 MB; h dead after quant_h */
#define OFF_NS    (OFF_H   + (size_t)M1*N1*4)           /* fp32 1536*64 */

__device__ __forceinline__ unsigned int enc_f(float f) {
    unsigned int u = __float_as_uint(f);
    return (u & 0x80000000u) ? ~u : (u | 0x80000000u);
}
__device__ __forceinline__ float dec_f(unsigned int u) {
    return __uint_as_float((u & 0x80000000u) ? (u & 0x7FFFFFFFu) : ~u);
}

/* init scal + zero bias accumulators (ws is poisoned 0xAA every launch) */
__global__ void k_init(unsigned int* scal, float* b1raw, float* b2raw) {
    int t = threadIdx.x;
    if (t == 0) { scal[0] = 0xFFFFFFFFu; scal[1] = 0u; scal[2] = 0xFFFFFFFFu; scal[3] = 0u; }
    if (t < N1) b1raw[t] = 0.f;
    if (t < N2) b2raw[t] = 0.f;
}

__global__ __launch_bounds__(256) void k_minmax_c1(const float* __restrict__ node,
                                                   const float* __restrict__ edge,
                                                   unsigned int* __restrict__ scal) {
    const int nn = B_*AT_*FN_;
    const int ntot = nn + M1*FE_;
    float mn = 3.0e38f, mx = -3.0e38f;
    for (int idx = blockIdx.x*blockDim.x + threadIdx.x; idx < ntot; idx += gridDim.x*blockDim.x) {
        float x = (idx < nn) ? node[idx] : edge[idx - nn];
        mn = fminf(mn, x); mx = fmaxf(mx, x);
    }
    __shared__ float smn[256], smx[256];
    smn[threadIdx.x] = mn; smx[threadIdx.x] = mx; __syncthreads();
    for (int s = 128; s > 0; s >>= 1) {
        if (threadIdx.x < s) {
            smn[threadIdx.x] = fminf(smn[threadIdx.x], smn[threadIdx.x+s]);
            smx[threadIdx.x] = fmaxf(smx[threadIdx.x], smx[threadIdx.x+s]);
        }
        __syncthreads();
    }
    if (threadIdx.x == 0) { atomicMin(&scal[0], enc_f(smn[0])); atomicMax(&scal[1], enc_f(smx[0])); }
}

/* expanded fp16 weights, o-major: We[o][k=i*8+b] = fp16( (w+0.1|w|eps_b) * 2^b * s )
   + fused bias-sum accumulation (wave-reduce, 1 atomic per wave):
     USE_SECOND=false: bias contrib = plane-7 noisy value (layer 1)
     USE_SECOND=true : bias contrib = w_clean[1][o][i]      (layer 2) */
template<int KQ, int N, int SBASE, bool USE_SECOND>
__global__ __launch_bounds__(256) void k_prep_w16(const float* __restrict__ w_clean,
                                                  const float* __restrict__ eps,
                                                  const unsigned int* __restrict__ scal,
                                                  float* __restrict__ braw,
                                                  _Float16* __restrict__ We) {
    int idx = blockIdx.x*blockDim.x + threadIdx.x;   /* one thread per (o,i) */
    if (idx >= N*KQ) return;
    int o = idx / KQ;
    int i = idx % KQ;
    float mn = dec_f(scal[SBASE]), mx = dec_f(scal[SBASE+1]);
    float s = (mx - mn) * (1.0f/255.0f);
    float w = w_clean[idx];
    float aw = fabsf(w) * 0.1f;
    union { _Float16 h[8]; uint4 u; } pk;
    float p = s;
    float v7 = 0.f;
    #pragma unroll
    for (int b = 0; b < 8; b++) {
        float e = eps[(size_t)b*N*KQ + idx];
        float v = w + e*aw;
        if (b == 7) v7 = v;
        pk.h[b] = (_Float16)(v * p);
        p *= 2.0f;
    }
    *(uint4*)&We[((size_t)o*KQ + i)*8] = pk.u;
    /* bias-sum: wave spans 64 consecutive i of one o (KQ multiple of 64) */
    float bv = USE_SECOND ? w_clean[(size_t)N*KQ + idx] : v7;
    #pragma unroll
    for (int off = 32; off > 0; off >>= 1) bv += __shfl_down(bv, off);
    if ((threadIdx.x & 63) == 0) atomicAdd(&braw[o], bv);
}

/* quantize c1 -> q1 m-major [m][128] bytes; thread per output dword */
__global__ __launch_bounds__(256) void k_quant_c1(const float* __restrict__ node,
                                                  const float* __restrict__ edge,
                                                  const unsigned int* __restrict__ scal,
                                                  unsigned int* __restrict__ q1) {
    int idx = blockIdx.x*256 + threadIdx.x;   /* < M1*32 */
    int m = idx >> 5, dw = idx & 31;
    const float mn = dec_f(scal[0]), rng = dec_f(scal[1]) - mn;
    float4 x;
    if (dw < 16) x = *(const float4*)&node[(m/NBR_)*FN_ + dw*4];
    else         x = *(const float4*)&edge[(size_t)m*FE_ + (dw-16)*4];
    unsigned int b0 = (unsigned char)(int)((x.x - mn) / rng * 255.0f);
    unsigned int b1 = (unsigned char)(int)((x.y - mn) / rng * 255.0f);
    unsigned int b2 = (unsigned char)(int)((x.z - mn) / rng * 255.0f);
    unsigned int b3 = (unsigned char)(int)((x.w - mn) / rng * 255.0f);
    q1[idx] = b0 | (b1 << 8) | (b2 << 16) | (b3 << 24);
}

/* quantize h -> q2 m-major [m][512] bytes */
__global__ __launch_bounds__(256) void k_quant_h(const float* __restrict__ h,
                                                 const unsigned int* __restrict__ scal,
                                                 unsigned int* __restrict__ q2) {
    int idx = blockIdx.x*256 + threadIdx.x;   /* < M1*128 */
    const float mn = dec_f(scal[2]), rng = dec_f(scal[3]) - mn;
    float4 x = *(const float4*)&h[(size_t)idx*4];
    unsigned int b0 = (unsigned char)(int)((x.x - mn) / rng * 255.0f);
    unsigned int b1 = (unsigned char)(int)((x.y - mn) / rng * 255.0f);
    unsigned int b2 = (unsigned char)(int)((x.z - mn) / rng * 255.0f);
    unsigned int b3 = (unsigned char)(int)((x.w - mn) / rng * 255.0f);
    q2[idx] = b0 | (b1 << 8) | (b2 << 16) | (b3 << 24);
}

__device__ __forceinline__ f16x8 expand_byte(unsigned int byte) {
    /* 8 bits -> 8 packed fp16 in {0.0, 1.0}; pairs via r2 = b | b<<15 */
    unsigned int r2 = byte | (byte << 15);
    union { unsigned int u[4]; f16x8 h; } t;
    t.u[0] = ( r2       & 0x00010001u) * 0x3C00u;
    t.u[1] = ((r2 >> 2) & 0x00010001u) * 0x3C00u;
    t.u[2] = ((r2 >> 4) & 0x00010001u) * 0x3C00u;
    t.u[3] = ((r2 >> 6) & 0x00010001u) * 0x3C00u;
    return t.h;
}

/* MFMA bit-plane GEMM, K-group-wave structure, double-buffered counted-vmcnt
   pipeline (T3/T4-lite, m201-style):
   Block tile 128m x 64n, 4 waves = 2 (m) x 2 (K-half); each wave 64x64 via
   4x4 frags of 16x16x32 f16, BK=128 planes per block-iter (64/K-group).
   Staging is ALL global_load_lds (B: 4x16B, A: 2x4B gather per wave), so the
   entire staging path lives in the vmcnt domain:
     iter t: issue 6 loads for t+1 -> back buffer; s_waitcnt vmcnt(6) retires
     exactly iter t's loads (t+1's stay in flight across the barrier); raw
     s_barrier; compute front buffer; lgkmcnt(0); s_barrier.
   Last iteration peeled (no tail loads -> nothing lands in LDS while the
   epilogue reuses Bs as reduction scratch).
   K-halves LDS-reduced at the end. Grid 1152 blocks; LDS 36 KB -> 4 blocks/CU. */
template<int KQ, int N, int SPLITK, bool EPI1>
__global__ __launch_bounds__(256, 4) void kg(const unsigned char* __restrict__ q,
                                             const _Float16* __restrict__ W,
                                             const float* __restrict__ braw,
                                             void* __restrict__ outv,
                                             unsigned int* __restrict__ scal) {
    constexpr int KP  = KQ * 8;        /* total bit-planes */
    constexpr int KPS = KP / SPLITK;   /* planes per z-split (1024 both layers) */
    constexpr int NIT = KPS / 128;     /* 8 */
    __shared__ _Float16 Bs[16384];     /* 32 KB: 2 x [kg][n][chunk^(n&7)] of 8 fp16 */
    __shared__ uint2    Qs[512];       /*  4 KB: 2 x [kg][m_local] 8 q bytes */

    const int tid  = threadIdx.x;
    const int lane = tid & 63;
    const int w    = tid >> 6;
    const int wm   = (w & 1) * 64;
    const int kg   = w >> 1;           /* K-group of this wave */
    const int l15  = lane & 15;
    const int lq   = lane >> 4;
    const int sh8  = lq * 8;
    const int m0   = blockIdx.x * 128;
    const int o0   = blockIdx.y * 64;
    const int kbase = blockIdx.z * KPS;

    f32x4 acc[4][4] = {};

    /* B-staging geometry: 4 x global_load_lds(16) per thread per iter.
       slot s = iss*256+tid covers (skg, n, chunk csrc) with csrc pre-swizzled
       so the linear LDS write realizes the XOR layout. */
    unsigned int bo[4];                 /* source offsets from W, in halves */
    #pragma unroll
    for (int iss = 0; iss < 4; ++iss) {
        int s = iss*256 + tid, skg = s >> 9, sg = s & 511, n = sg >> 3;
        int csrc = (sg & 7) ^ (n & 7);
        bo[iss] = (unsigned int)((o0 + n)*KP + kbase + skg*512 + csrc*8);
    }
    const int bdl = (tid & ~63) * 8;    /* LDS dest (halves), wave-uniform */

    /* A-staging geometry: 2 x global_load_lds(4) per wave per iter.
       dword d = w*128 + i*64 + lane  ->  kg=d>>8, row=(d>>1)&127, half=d&1 */
    unsigned int ao[2];                 /* source byte offsets from q */
    #pragma unroll
    for (int i = 0; i < 2; ++i) {
        int d = w*128 + i*64 + lane;
        int kga = d >> 8, row = (d >> 1) & 127, half = d & 1;
        ao[i] = (unsigned int)((m0 + row)*KQ + (kbase >> 3) + kga*64 + half*4);
    }
    const int adl = w * 512;            /* LDS dest (bytes), wave-uniform */

    auto stage = [&](int IT, int BUF) {
        #pragma unroll
        for (int iss = 0; iss < 4; ++iss)
            __builtin_amdgcn_global_load_lds((gconst_void*)(W + bo[iss] + IT*64),
                (lds_void*)(Bs + BUF*8192 + iss*2048 + bdl), 16, 0, 0);
        #pragma unroll
        for (int i = 0; i < 2; ++i)
            __builtin_amdgcn_global_load_lds((gconst_void*)(q + ao[i] + IT*8),
                (lds_void*)((char*)Qs + BUF*2048 + i*256 + adl), 4, 0, 0);
    };

    auto compute = [&](int cur) {
        const _Float16* Bc = Bs + cur*8192 + kg*4096;
        const uint2*    Qc = Qs + cur*256 + kg*128;
        uint2 qd[4];
        #pragma unroll
        for (int mf = 0; mf < 4; ++mf)
            qd[mf] = Qc[wm + mf*16 + l15];
        #pragma unroll
        for (int kf = 0; kf < 2; ++kf) {
            f16x8 bf[4];
            #pragma unroll
            for (int nf = 0; nf < 4; ++nf) {
                const int nl = nf*16 + l15;
                const int ch = kf*4 + lq;
                bf[nf] = *(const f16x8*)&Bc[nl*64 + ((ch ^ (nl & 7)) << 3)];
            }
            #pragma unroll
            for (int mf = 0; mf < 4; ++mf) {
                unsigned int byte = ((kf ? qd[mf].y : qd[mf].x) >> sh8) & 0xFFu;
                f16x8 a = expand_byte(byte);
                #pragma unroll
                for (int nf = 0; nf < 4; ++nf)
                    acc[mf][nf] = __builtin_amdgcn_mfma_f32_16x16x32_f16(a, bf[nf], acc[mf][nf], 0, 0, 0);
            }
        }
    };

    stage(0, 0);
    #pragma unroll 1
    for (int it = 0; it < NIT-1; ++it) {
        const int cur = it & 1;
        stage(it+1, cur ^ 1);
        asm volatile("s_waitcnt vmcnt(6)" ::: "memory");  /* retire iter it's 6; keep it+1's in flight */
        asm volatile("s_barrier" ::: "memory");
        compute(cur);
        asm volatile("s_waitcnt lgkmcnt(0)" ::: "memory"); /* pin ds_read retirement before reuse barrier */
        asm volatile("s_barrier" ::: "memory");
    }
    asm volatile("s_waitcnt vmcnt(0)" ::: "memory");
    asm volatile("s_barrier" ::: "memory");
    compute((NIT-1) & 1);

    /* K-group reduction: kg=1 waves hand their acc to kg=0 partners via LDS */
    float* red = (float*)Bs;
    #pragma unroll
    for (int nf = 0; nf < 4; ++nf) {
        __syncthreads();
        if (kg == 1) {
            #pragma unroll
            for (int mf = 0; mf < 4; ++mf)
                *(f32x4*)&red[(w & 1)*1024 + mf*256 + lane*4] = acc[mf][nf];
        }
        __syncthreads();
        if (kg == 0) {
            #pragma unroll
            for (int mf = 0; mf < 4; ++mf)
                acc[mf][nf] += *(const f32x4*)&red[(w & 1)*1024 + mf*256 + lane*4];
        }
    }

    /* epilogue: C/D layout col = lane&15, row = (lane>>4)*4 + r  (m89) */
    if (EPI1) {
        float tmn = 3.0e38f, tmx = -3.0e38f;
        if (kg == 0) {
            float* out = (float*)outv;
            const float mn1 = dec_f(scal[0]);
            float bv[4];
            #pragma unroll
            for (int nf = 0; nf < 4; ++nf) bv[nf] = mn1 * braw[o0 + nf*16 + l15];
            #pragma unroll
            for (int mf = 0; mf < 4; ++mf) {
                const int mr = m0 + wm + mf*16 + lq*4;
                #pragma unroll
                for (int nf = 0; nf < 4; ++nf) {
                    const int oc = o0 + nf*16 + l15;
                    #pragma unroll
                    for (int r = 0; r < 4; ++r) {
                        float v = acc[mf][nf][r] + bv[nf];
                        v = fmaxf(v, 0.0f);
                        tmn = fminf(tmn, v); tmx = fmaxf(tmx, v);
                        out[(size_t)(mr + r)*N + oc] = v;
                    }
                }
            }
        }
        __syncthreads();
        red[tid] = tmn; red[256 + tid] = tmx;
        __syncthreads();
        for (int s = 128; s > 0; s >>= 1) {
            if (tid < s) {
                red[tid]       = fminf(red[tid],       red[tid + s]);
                red[256 + tid] = fmaxf(red[256 + tid], red[256 + tid + s]);
            }
            __syncthreads();
        }
        if (tid == 0) { atomicMin(&scal[2], enc_f(red[0])); atomicMax(&scal[3], enc_f(red[256])); }
    } else {
        if (kg == 0) {
            _Float16* op = (_Float16*)outv + (size_t)blockIdx.z * ((size_t)M1 * N);
            #pragma unroll
            for (int mf = 0; mf < 4; ++mf) {
                const int mr = m0 + wm + mf*16 + lq*4;
                #pragma unroll
                for (int nf = 0; nf < 4; ++nf) {
                    const int oc = o0 + nf*16 + l15;
                    #pragma unroll
                    for (int r = 0; r < 4; ++r)
                        op[(size_t)(mr + r)*N + oc] = (_Float16)acc[mf][nf][r];
                }
            }
        }
    }
}

/* gate/extract from fp16 split-K partials -> sigmoid*tanh*mask, sum over neighbors */
__global__ __launch_bounds__(256) void k_nbr(const _Float16* __restrict__ zp,
                                             const float* __restrict__ b2raw,
                                             const unsigned int* __restrict__ scal,
                                             const float* __restrict__ mask,
                                             float* __restrict__ ns) {
    const size_t SP = (size_t)M1 * N2;
    int tid = threadIdx.x;
    int r = blockIdx.x*4 + (tid >> 6);   /* 0..1535 */
    int f = tid & 63;
    const float mn2 = dec_f(scal[2]);
    float bg = mn2 * b2raw[f], be = mn2 * b2raw[64 + f];
    float s = 0.f;
    #pragma unroll
    for (int n = 0; n < NBR_; n++) {
        int m = r*NBR_ + n;
        size_t base = (size_t)m * N2;
        float g = bg, e = be;
        #pragma unroll
        for (int z = 0; z < SPLIT2; z++) {
            g += (float)zp[z*SP + base + f];
            e += (float)zp[z*SP + base + 64 + f];
        }
        float sig = 1.0f / (1.0f + expf(-g));
        s += sig * tanhf(e) * mask[m];
    }
    ns[r*64 + f] = s;
}

/* BatchNorm (batch stats over 1536 rows) + residual + relu; one block per feature */
__global__ __launch_bounds__(256) void k_bn(const float* __restrict__ ns,
                                            const float* __restrict__ node,
                                            const float* __restrict__ gamma,
                                            const float* __restrict__ beta,
                                            float* __restrict__ out) {
    int f = blockIdx.x;
    int tid = threadIdx.x;
    float x[6];
    float s = 0.f, ss = 0.f;
    #pragma unroll
    for (int k = 0; k < 6; k++) {
        int r = tid + k*256;
        x[k] = ns[r*64 + f];
        s += x[k]; ss += x[k]*x[k];
    }
    __shared__ float rs[256], rss[256];
    rs[tid] = s; rss[tid] = ss; __syncthreads();
    for (int st = 128; st > 0; st >>= 1) {
        if (tid < st) { rs[tid] += rs[tid+st]; rss[tid] += rss[tid+st]; }
        __syncthreads();
    }
    float mean = rs[0] / 1536.0f;
    float var  = rss[0] / 1536.0f - mean*mean;
    float denom = sqrtf(var + 1e-5f);
    float g = gamma[f], bt = beta[f];
    #pragma unroll
    for (int k = 0; k < 6; k++) {
        int r = tid + k*256;
        float v = node[r*64 + f] + ((x[k] - mean) / denom * g + bt);
        out[r*64 + f] = fmaxf(v, 0.f);
    }
}

extern "C" void kernel_launch(void* const* d_in, const int* in_sizes, int n_in,
                              void* d_out, int out_size, void* d_ws, size_t ws_size,
                              hipStream_t stream) {
    const float* node  = (const float*)d_in[0];
    const float* edge  = (const float*)d_in[1];
    const float* mask  = (const float*)d_in[2];
    const float* cond1 = (const float*)d_in[3];
    const float* cond2 = (const float*)d_in[4];
    const float* eps1  = (const float*)d_in[5];
    const float* eps2  = (const float*)d_in[6];
    const float* gamma = (const float*)d_in[7];
    const float* beta  = (const float*)d_in[8];
    float* out = (float*)d_out;
    char* ws = (char*)d_ws;

    unsigned int*  scal = (unsigned int*)(ws + OFF_SCAL);
    float* b1raw = (float*)(ws + OFF_B1R);
    float* b2raw = (float*)(ws + OFF_B2R);
    unsigned char* q1 = (unsigned char*)(ws + OFF_Q1);
    _Float16* W1e = (_Float16*)(ws + OFF_W1E);
    _Float16* W2e = (_Float16*)(ws + OFF_W2E);
    unsigned char* q2 = (unsigned char*)(ws + OFF_Q2);
    float*    h  = (float*)(ws + OFF_H);
    _Float16* zp = (_Float16*)(ws + OFF_ZP);
    float*    ns = (float*)(ws + OFF_NS);

    k_init<<<1, 1024, 0, stream>>>(scal, b1raw, b2raw);
    k_minmax_c1<<<512, 256, 0, stream>>>(node, edge, scal);
    k_prep_w16<K1Q, N1, 0, false><<<(N1*K1Q + 255)/256, 256, 0, stream>>>(cond1, eps1, scal, b1raw, W1e);
    k_quant_c1<<<(M1*32)/256, 256, 0, stream>>>(node, edge, scal, (unsigned int*)q1);
    kg<K1Q, N1, 1, true><<<dim3(M1/128, N1/64, 1), 256, 0, stream>>>(q1, W1e, b1raw, h, scal);
    k_prep_w16<K2Q, N2, 2, true><<<(N2*K2Q + 255)/256, 256, 0, stream>>>(cond2, eps2, scal, b2raw, W2e);
    k_quant_h<<<(M1*128)/256, 256, 0, stream>>>(h, scal, (unsigned int*)q2);
    kg<K2Q, N2, SPLIT2, false><<<dim3(M1/128, N2/64, SPLIT2), 256, 0, stream>>>(q2, W2e, b2raw, zp, scal);
    k_nbr<<<R_/4, 256, 0, stream>>>(zp, b2raw, scal, mask, ns);
    k_bn<<<64, 256, 0, stream>>>(ns, node, gamma, beta, out);
}